// Round 10
// baseline (437.875 us; speedup 1.0000x reference)
//
#include <hip/hip_runtime.h>

typedef __bf16 bf16x8 __attribute__((ext_vector_type(8)));
typedef float f32x4 __attribute__((ext_vector_type(4)));
typedef float f32x2 __attribute__((ext_vector_type(2)));

static constexpr int TOKS = 43520;   // B * LQ
static constexpr int LQN  = 21760;

__device__ __forceinline__ unsigned short f2bf(float f) {
  union { float f; unsigned u; } v; v.f = f;
  return (unsigned short)((v.u + 0x7fffu + ((v.u >> 16) & 1u)) >> 16);
}
__device__ __forceinline__ float bf2f(unsigned short b) {
  union { unsigned u; float f; } v; v.u = ((unsigned)b) << 16; return v.f;
}

// ---- fused prep + LDS-tiled weight transpose (coalesced stores) + bias concat
__global__ __launch_bounds__(256) void prewt_kernel(
    const float* __restrict__ src, const float* __restrict__ pos,
    unsigned short* __restrict__ srcb, unsigned short* __restrict__ qb,
    const float* __restrict__ W_val, const float* __restrict__ W_off,
    const float* __restrict__ W_attn, const float* __restrict__ W_out,
    const float* __restrict__ W1, const float* __restrict__ W2,
    const float* __restrict__ b_off, const float* __restrict__ b_attn,
    unsigned short* __restrict__ Wt_val, unsigned short* __restrict__ Wt_oa,
    unsigned short* __restrict__ Wt_out,
    unsigned short* __restrict__ Wt_1, unsigned short* __restrict__ Wt_2,
    float* __restrict__ b_oa) {
  const int bid = blockIdx.x;
  const int t = threadIdx.x;
  if (bid < 10880) {
    int i = bid * 256 + t;
    float4 s = ((const float4*)src)[i], p = ((const float4*)pos)[i];
    ((ushort4*)srcb)[i] = make_ushort4(f2bf(s.x), f2bf(s.y), f2bf(s.z), f2bf(s.w));
    ((ushort4*)qb)[i]   = make_ushort4(f2bf(s.x + p.x), f2bf(s.y + p.y),
                                       f2bf(s.z + p.z), f2bf(s.w + p.w));
    return;
  }
  if (bid == 11616) {                  // bias concat
    b_oa[t] = (t < 256) ? b_off[t] : 0.f;
    if (t >= 256) return;
    if (t < 128) b_oa[256 + t] = b_attn[t];
    return;
  }
  // ---- 32x32 tiled transpose: W [Kd][Nd] f32 -> Wt [Nd][Kd] bf16
  int tid = bid - 10880;               // 0..735
  const float* W; unsigned short* Wt; int Kd, Nd, nshn;
  if (tid < 64)        {            W = W_val;  Wt = Wt_val;         Kd = 256;  Nd = 256;  nshn = 3; }
  else if (tid < 128)  { tid -= 64; W = W_off;  Wt = Wt_oa;          Kd = 256;  Nd = 256;  nshn = 3; }
  else if (tid < 160)  { tid -= 128;W = W_attn; Wt = Wt_oa + 65536;  Kd = 256;  Nd = 128;  nshn = 2; }
  else if (tid < 224)  { tid -= 160;W = W_out;  Wt = Wt_out;         Kd = 256;  Nd = 256;  nshn = 3; }
  else if (tid < 480)  { tid -= 224;W = W1;     Wt = Wt_1;           Kd = 256;  Nd = 1024; nshn = 5; }
  else                 { tid -= 480;W = W2;     Wt = Wt_2;           Kd = 1024; Nd = 256;  nshn = 3; }
  const int k0 = (tid >> nshn) * 32;
  const int n0 = (tid & ((1 << nshn) - 1)) * 32;
  __shared__ float tileT[32][33];
  {
    const int kl = t >> 3, nc = (t & 7) * 4;
    float4 v = *(const float4*)&W[(size_t)(k0 + kl) * Nd + n0 + nc];
    tileT[nc + 0][kl] = v.x; tileT[nc + 1][kl] = v.y;
    tileT[nc + 2][kl] = v.z; tileT[nc + 3][kl] = v.w;
  }
  __syncthreads();
  {
    const int nl = t >> 3, kc = (t & 7) * 4;
    ushort4 o = make_ushort4(f2bf(tileT[nl][kc + 0]), f2bf(tileT[nl][kc + 1]),
                             f2bf(tileT[nl][kc + 2]), f2bf(tileT[nl][kc + 3]));
    *(ushort4*)&Wt[(size_t)(n0 + nl) * Kd + k0 + kc] = o;
  }
}

// ---- R2-proven 128x128 GEMM body: padded LDS, reg staging, ONE barrier per K-iter.
template <int K, int OUTOP>
__device__ __forceinline__ void gemm_body(unsigned short* __restrict__ As,
                                          unsigned short* __restrict__ Bs,
                                          const unsigned short* __restrict__ A,
                                          const unsigned short* __restrict__ Bt,
                                          const float* __restrict__ bias,
                                          const unsigned short* __restrict__ res,
                                          unsigned short* __restrict__ Cp,
                                          int N, int bm, int bn) {
  const int t = threadIdx.x;
  const int wave = t >> 6, lane = t & 63;
  const int wm = (wave & 1) << 6, wn = (wave >> 1) << 6;
  const int lr = lane & 15, lq = lane >> 4;
  const int row0 = t >> 2, cb0 = (t & 3) << 3;
  f32x4 acc[4][4] = {};
  const unsigned short* ga = A  + (size_t)(bm * 128 + row0) * K + cb0;
  const unsigned short* gb = Bt + (size_t)(bn * 128 + row0) * K + cb0;
  const size_t gs = (size_t)64 * K;
  uint4 pa0 = *(const uint4*)ga;
  uint4 pa1 = *(const uint4*)(ga + gs);
  uint4 pb0 = *(const uint4*)gb;
  uint4 pb1 = *(const uint4*)(gb + gs);
  int p = 0;
#pragma unroll 1
  for (int k0 = 0; k0 < K; k0 += 32) {
    unsigned short* Ab = As + p * 5120;
    unsigned short* Bb = Bs + p * 5120;
    *(uint4*)&Ab[row0 * 40 + cb0] = pa0;
    *(uint4*)&Ab[(row0 + 64) * 40 + cb0] = pa1;
    *(uint4*)&Bb[row0 * 40 + cb0] = pb0;
    *(uint4*)&Bb[(row0 + 64) * 40 + cb0] = pb1;
    __syncthreads();
    if (k0 + 32 < K) {
      pa0 = *(const uint4*)(ga + k0 + 32);
      pa1 = *(const uint4*)(ga + gs + k0 + 32);
      pb0 = *(const uint4*)(gb + k0 + 32);
      pb1 = *(const uint4*)(gb + gs + k0 + 32);
    }
    bf16x8 af[4], bfr[4];
#pragma unroll
    for (int i = 0; i < 4; i++) af[i] = *(const bf16x8*)&Ab[(wm + i * 16 + lr) * 40 + lq * 8];
#pragma unroll
    for (int j = 0; j < 4; j++) bfr[j] = *(const bf16x8*)&Bb[(wn + j * 16 + lr) * 40 + lq * 8];
#pragma unroll
    for (int i = 0; i < 4; i++)
#pragma unroll
      for (int j = 0; j < 4; j++)
        acc[i][j] = __builtin_amdgcn_mfma_f32_16x16x32_bf16(af[i], bfr[j], acc[i][j], 0, 0, 0);
    p ^= 1;
  }
  const int rb = bm * 128 + wm + lq * 4;
  const int cbase = bn * 128 + wn + lr;
#pragma unroll
  for (int j = 0; j < 4; j++) {
    const int col = cbase + j * 16;
    const float bv = bias[col];
#pragma unroll
    for (int i = 0; i < 4; i++) {
#pragma unroll
      for (int r = 0; r < 4; r++) {
        float v = acc[i][j][r] + bv;
        size_t o = (size_t)(rb + i * 16 + r) * N + col;
        if (OUTOP == 1) Cp[o] = f2bf(v);
        else if (OUTOP == 2) Cp[o] = f2bf(fmaxf(v, 0.f));
        else Cp[o] = f2bf(v + bf2f(res[o]));
      }
    }
  }
}

__global__ __launch_bounds__(256) void proj_kernel(
    const unsigned short* __restrict__ srcb, const unsigned short* __restrict__ qb,
    const unsigned short* __restrict__ Wt_val, const unsigned short* __restrict__ Wt_oa,
    const float* __restrict__ b_val, const float* __restrict__ b_oa,
    unsigned short* __restrict__ valb, unsigned short* __restrict__ oab) {
  __shared__ unsigned short As[2 * 5120];
  __shared__ unsigned short Bs[2 * 5120];
  const int bn = blockIdx.y;
  if (bn < 2)
    gemm_body<256, 1>(As, Bs, srcb, Wt_val, b_val, nullptr, valb, 256, blockIdx.x, bn);
  else
    gemm_body<256, 1>(As, Bs, qb, Wt_oa, b_oa, nullptr, oab, 384, blockIdx.x, bn - 2);
}

// ---- value relayout: valb [tok][8h][32d] -> valbH [8h][tok][32d] (64B rows).
// Makes x-adjacent bilinear corners land in ONE 128B line during deform's gather.
__global__ __launch_bounds__(256) void vrelay_kernel(const unsigned short* __restrict__ valb,
                                                     unsigned short* __restrict__ valbH) {
  const int t = threadIdx.x;
  const int tok = blockIdx.x * 32 + (t & 31);
  const int h = t >> 5;
  const uint4* s = (const uint4*)(valb + (size_t)tok * 256 + h * 32);
  uint4* d = (uint4*)(valbH + ((size_t)h * TOKS + tok) * 32);
  d[0] = s[0]; d[1] = s[1]; d[2] = s[2]; d[3] = s[3];
}

// ---- fused tail (R8-proven): out-proj + res(src) + LN1 + FFN + res(h) + LN2.
__global__ __launch_bounds__(256, 3) void fused_tail_kernel(
    const unsigned short* __restrict__ attn,
    const unsigned short* __restrict__ Wot,
    const float* __restrict__ b_out,
    const unsigned short* __restrict__ srcres,
    const float* __restrict__ g1, const float* __restrict__ be1,
    const unsigned short* __restrict__ W1t,
    const unsigned short* __restrict__ W2t,
    const float* __restrict__ b1, const float* __restrict__ b2,
    const float* __restrict__ g2, const float* __restrict__ be2,
    float* __restrict__ out) {
  __shared__ unsigned short Ah[64 * 264];
  __shared__ unsigned short Hc[64 * 136];
  __shared__ float red[2][4][64];
  const int t = threadIdx.x;
  const int w = t >> 6, lane = t & 63;
  const int lr = lane & 15, lq = lane >> 4;
  const size_t rowbase = (size_t)blockIdx.x * 64;

  {
    const uint4* gsrc = (const uint4*)(attn + rowbase * 256);
#pragma unroll
    for (int u = 0; u < 8; u++) {
      const int idx = u * 256 + t;
      const int row = idx >> 5, c8 = idx & 31;
      *(uint4*)&Ah[row * 264 + c8 * 8] = gsrc[idx];
    }
  }
  __syncthreads();

  // ---- GEMM0: out-proj (K=256), depth-2 weight prefetch, full unroll
  f32x4 acc0[4][4] = {};
  {
    const size_t wb = (size_t)(w * 64 + lr) * 256 + lq * 8;
    bf16x8 wf0[2][4];
#pragma unroll
    for (int d = 0; d < 2; d++)
#pragma unroll
      for (int j = 0; j < 4; j++)
        wf0[d][j] = *(const bf16x8*)&Wot[wb + (size_t)j * 4096 + d * 32];
#pragma unroll
    for (int ks = 0; ks < 8; ks++) {
      bf16x8 c0 = wf0[ks & 1][0], c1 = wf0[ks & 1][1];
      bf16x8 c2 = wf0[ks & 1][2], c3 = wf0[ks & 1][3];
      if (ks + 2 < 8) {
#pragma unroll
        for (int j = 0; j < 4; j++)
          wf0[ks & 1][j] = *(const bf16x8*)&Wot[wb + (size_t)j * 4096 + (ks + 2) * 32];
      }
      bf16x8 af[4];
#pragma unroll
      for (int i = 0; i < 4; i++)
        af[i] = *(const bf16x8*)&Ah[(i * 16 + lr) * 264 + ks * 32 + lq * 8];
#pragma unroll
      for (int i = 0; i < 4; i++) {
        acc0[i][0] = __builtin_amdgcn_mfma_f32_16x16x32_bf16(af[i], c0, acc0[i][0], 0, 0, 0);
        acc0[i][1] = __builtin_amdgcn_mfma_f32_16x16x32_bf16(af[i], c1, acc0[i][1], 0, 0, 0);
        acc0[i][2] = __builtin_amdgcn_mfma_f32_16x16x32_bf16(af[i], c2, acc0[i][2], 0, 0, 0);
        acc0[i][3] = __builtin_amdgcn_mfma_f32_16x16x32_bf16(af[i], c3, acc0[i][3], 0, 0, 0);
      }
    }
  }
  // ---- epilogue0: +b_out +res(src) ; LN1 ; h -> Ah (bf16, in place)
  {
    float vsum[4][4], vsq[4][4];
#pragma unroll
    for (int i = 0; i < 4; i++)
#pragma unroll
      for (int r = 0; r < 4; r++) { vsum[i][r] = 0.f; vsq[i][r] = 0.f; }
#pragma unroll
    for (int j = 0; j < 4; j++) {
      const int col = w * 64 + j * 16 + lr;
      const float bv = b_out[col];
#pragma unroll
      for (int i = 0; i < 4; i++)
#pragma unroll
        for (int r = 0; r < 4; r++) {
          const int row = i * 16 + lq * 4 + r;
          float v = acc0[i][j][r] + bv + bf2f(srcres[(rowbase + row) * 256 + col]);
          acc0[i][j][r] = v;
          vsum[i][r] += v;
          vsq[i][r]  += v * v;
        }
    }
#pragma unroll
    for (int m = 1; m <= 8; m <<= 1)
#pragma unroll
      for (int i = 0; i < 4; i++)
#pragma unroll
        for (int r = 0; r < 4; r++) {
          vsum[i][r] += __shfl_xor(vsum[i][r], m, 64);
          vsq[i][r]  += __shfl_xor(vsq[i][r],  m, 64);
        }
    if (lr == 0) {
#pragma unroll
      for (int i = 0; i < 4; i++)
#pragma unroll
        for (int r = 0; r < 4; r++) {
          const int row = i * 16 + lq * 4 + r;
          red[0][w][row] = vsum[i][r];
          red[1][w][row] = vsq[i][r];
        }
    }
    __syncthreads();
    float mu[4][4], rstd[4][4];
#pragma unroll
    for (int i = 0; i < 4; i++)
#pragma unroll
      for (int r = 0; r < 4; r++) {
        const int row = i * 16 + lq * 4 + r;
        const float ts = red[0][0][row] + red[0][1][row] + red[0][2][row] + red[0][3][row];
        const float tq = red[1][0][row] + red[1][1][row] + red[1][2][row] + red[1][3][row];
        const float m_ = ts * (1.f / 256.f);
        mu[i][r] = m_;
        rstd[i][r] = rsqrtf(tq * (1.f / 256.f) - m_ * m_ + 1e-5f);
      }
#pragma unroll
    for (int j = 0; j < 4; j++) {
      const int col = w * 64 + j * 16 + lr;
      const float gg = g1[col], bb = be1[col];
#pragma unroll
      for (int i = 0; i < 4; i++)
#pragma unroll
        for (int r = 0; r < 4; r++) {
          const int row = i * 16 + lq * 4 + r;
          const float y = (acc0[i][j][r] - mu[i][r]) * rstd[i][r] * gg + bb;
          Ah[row * 264 + col] = f2bf(y);
        }
    }
  }
  __syncthreads();

  // ---- FFN: 8 chunks of 128 hidden cols; deep weight prefetch
  f32x4 acc2[4][4] = {};
  const int c1base = w * 32;
#pragma unroll 1
  for (int c2 = 0; c2 < 8; c2++) {
    f32x4 acc1[4][2] = {};
    const size_t w1r0 = (size_t)(c2 * 128 + c1base + lr) * 256 + lq * 8;
    const size_t w1r1 = w1r0 + (size_t)16 * 256;
    bf16x8 wf[4][2];
#pragma unroll
    for (int d = 0; d < 4; d++) {
      wf[d][0] = *(const bf16x8*)&W1t[w1r0 + d * 32];
      wf[d][1] = *(const bf16x8*)&W1t[w1r1 + d * 32];
    }
#pragma unroll
    for (int ks = 0; ks < 8; ks++) {
      bf16x8 b0 = wf[ks & 3][0], b1v = wf[ks & 3][1];
      if (ks + 4 < 8) {
        wf[ks & 3][0] = *(const bf16x8*)&W1t[w1r0 + (ks + 4) * 32];
        wf[ks & 3][1] = *(const bf16x8*)&W1t[w1r1 + (ks + 4) * 32];
      }
      bf16x8 af[4];
#pragma unroll
      for (int i = 0; i < 4; i++)
        af[i] = *(const bf16x8*)&Ah[(i * 16 + lr) * 264 + ks * 32 + lq * 8];
#pragma unroll
      for (int i = 0; i < 4; i++) {
        acc1[i][0] = __builtin_amdgcn_mfma_f32_16x16x32_bf16(af[i], b0,  acc1[i][0], 0, 0, 0);
        acc1[i][1] = __builtin_amdgcn_mfma_f32_16x16x32_bf16(af[i], b1v, acc1[i][1], 0, 0, 0);
      }
    }
    __syncthreads();
#pragma unroll
    for (int j = 0; j < 2; j++) {
      const int colc = c1base + j * 16 + lr;
      const float bv = b1[c2 * 128 + colc];
#pragma unroll
      for (int i = 0; i < 4; i++)
#pragma unroll
        for (int r = 0; r < 4; r++)
          Hc[(i * 16 + lq * 4 + r) * 136 + colc] = f2bf(fmaxf(acc1[i][j][r] + bv, 0.f));
    }
    __syncthreads();
    const size_t w2b = (size_t)(w * 64 + lr) * 1024 + c2 * 128 + lq * 8;
    bf16x8 wg[2][4];
#pragma unroll
    for (int d = 0; d < 2; d++)
#pragma unroll
      for (int j = 0; j < 4; j++)
        wg[d][j] = *(const bf16x8*)&W2t[w2b + (size_t)j * 16384 + d * 32];
#pragma unroll
    for (int ks = 0; ks < 4; ks++) {
      bf16x8 c0 = wg[ks & 1][0], c1 = wg[ks & 1][1];
      bf16x8 cc2 = wg[ks & 1][2], c3 = wg[ks & 1][3];
      if (ks + 2 < 4) {
#pragma unroll
        for (int j = 0; j < 4; j++)
          wg[ks & 1][j] = *(const bf16x8*)&W2t[w2b + (size_t)j * 16384 + (ks + 2) * 32];
      }
      bf16x8 af2[4];
#pragma unroll
      for (int i = 0; i < 4; i++)
        af2[i] = *(const bf16x8*)&Hc[(i * 16 + lr) * 136 + ks * 32 + lq * 8];
#pragma unroll
      for (int i = 0; i < 4; i++) {
        acc2[i][0] = __builtin_amdgcn_mfma_f32_16x16x32_bf16(af2[i], c0,  acc2[i][0], 0, 0, 0);
        acc2[i][1] = __builtin_amdgcn_mfma_f32_16x16x32_bf16(af2[i], c1,  acc2[i][1], 0, 0, 0);
        acc2[i][2] = __builtin_amdgcn_mfma_f32_16x16x32_bf16(af2[i], cc2, acc2[i][2], 0, 0, 0);
        acc2[i][3] = __builtin_amdgcn_mfma_f32_16x16x32_bf16(af2[i], c3,  acc2[i][3], 0, 0, 0);
      }
    }
  }
  // ---- epilogue2: +b2 +res(h from Ah) ; LN2 ; f32 out
  float vsum[4][4], vsq[4][4];
#pragma unroll
  for (int i = 0; i < 4; i++)
#pragma unroll
    for (int r = 0; r < 4; r++) { vsum[i][r] = 0.f; vsq[i][r] = 0.f; }
#pragma unroll
  for (int j = 0; j < 4; j++) {
    const int col = w * 64 + j * 16 + lr;
    const float bv = b2[col];
#pragma unroll
    for (int i = 0; i < 4; i++)
#pragma unroll
      for (int r = 0; r < 4; r++) {
        const int row = i * 16 + lq * 4 + r;
        float v = acc2[i][j][r] + bv + bf2f(Ah[row * 264 + col]);
        acc2[i][j][r] = v;
        vsum[i][r] += v;
        vsq[i][r]  += v * v;
      }
  }
#pragma unroll
  for (int m = 1; m <= 8; m <<= 1)
#pragma unroll
    for (int i = 0; i < 4; i++)
#pragma unroll
      for (int r = 0; r < 4; r++) {
        vsum[i][r] += __shfl_xor(vsum[i][r], m, 64);
        vsq[i][r]  += __shfl_xor(vsq[i][r],  m, 64);
      }
  __syncthreads();
  if (lr == 0) {
#pragma unroll
    for (int i = 0; i < 4; i++)
#pragma unroll
      for (int r = 0; r < 4; r++) {
        const int row = i * 16 + lq * 4 + r;
        red[0][w][row] = vsum[i][r];
        red[1][w][row] = vsq[i][r];
      }
  }
  __syncthreads();
  float mu[4][4], rstd[4][4];
#pragma unroll
  for (int i = 0; i < 4; i++)
#pragma unroll
    for (int r = 0; r < 4; r++) {
      const int row = i * 16 + lq * 4 + r;
      const float ts = red[0][0][row] + red[0][1][row] + red[0][2][row] + red[0][3][row];
      const float tq = red[1][0][row] + red[1][1][row] + red[1][2][row] + red[1][3][row];
      const float m_ = ts * (1.f / 256.f);
      mu[i][r] = m_;
      rstd[i][r] = rsqrtf(tq * (1.f / 256.f) - m_ * m_ + 1e-5f);
    }
#pragma unroll
  for (int j = 0; j < 4; j++) {
    const int col = w * 64 + j * 16 + lr;
    const float gg = g2[col], bb = be2[col];
#pragma unroll
    for (int i = 0; i < 4; i++)
#pragma unroll
      for (int r = 0; r < 4; r++) {
        const int row = i * 16 + lq * 4 + r;
        out[(rowbase + row) * 256 + col] = (acc2[i][j][r] - mu[i][r]) * rstd[i][r] * gg + bb;
      }
  }
}

// ---- bf16x8 (uint4) fused unpack + PACKED FMA (v_pk_fma_f32) into f32x2 acc
__device__ __forceinline__ void fma8(uint4 v, float w, f32x2* a) {
  const unsigned uu[4] = {v.x, v.y, v.z, v.w};
  const f32x2 w2 = {w, w};
#pragma unroll
  for (int i = 0; i < 4; i++) {
    union { unsigned u; float f; } lo, hi;
    lo.u = uu[i] << 16;
    hi.u = uu[i] & 0xffff0000u;
    f32x2 val = {lo.f, hi.f};
    a[i] += w2 * val;
  }
}

// ---- deformable attention over HEAD-MAJOR values valbH [8][TOKS][32]:
// token-head row = 64B; x-adjacent corners are adjacent 64B blocks (one 128B line).
__global__ __launch_bounds__(256) void deform_kernel(const unsigned short* __restrict__ valbH,
                                                     const unsigned short* __restrict__ oab,
                                                     const float* __restrict__ refp,
                                                     unsigned short* __restrict__ outb) {
  __shared__ float4 sW[8][8][17];
  __shared__ int4   sI[8][8][17];
  const int t = threadIdx.x;
  const int bid = blockIdx.x;
  const int nb = (bid & 7) * 680 + (bid >> 3);
  const int tok0 = nb * 8;

  {
    const int g = t >> 5, h = (t >> 2) & 7, l = t & 3;
    const int tok = tok0 + g;
    const unsigned short* lg = oab + (size_t)tok * 384 + 256 + h * 16;
    uint4 lv0 = ((const uint4*)lg)[0];
    uint4 lv1 = ((const uint4*)lg)[1];
    const unsigned lw[8] = {lv0.x, lv0.y, lv0.z, lv0.w, lv1.x, lv1.y, lv1.z, lv1.w};
    float w[16];
#pragma unroll
    for (int i = 0; i < 8; i++) {
      union { unsigned u; float f; } lo, hi;
      lo.u = lw[i] << 16; hi.u = lw[i] & 0xffff0000u;
      w[2 * i] = lo.f; w[2 * i + 1] = hi.f;
    }
    float mx = -1e30f;
#pragma unroll
    for (int i = 0; i < 16; i++) mx = fmaxf(mx, w[i]);
    float s = 0.f;
#pragma unroll
    for (int i = 0; i < 16; i++) { w[i] = __expf(w[i] - mx); s += w[i]; }
    const float inv = 1.f / s;
    uint4 ov = *(const uint4*)(oab + (size_t)tok * 384 + h * 32 + l * 8);
    const unsigned owv[4] = {ov.x, ov.y, ov.z, ov.w};
    float off[8];
#pragma unroll
    for (int i = 0; i < 4; i++) {
      union { unsigned u; float f; } lo, hi;
      lo.u = owv[i] << 16; hi.u = owv[i] & 0xffff0000u;
      off[2 * i] = lo.f; off[2 * i + 1] = hi.f;
    }
    const float* rp = refp + (size_t)tok * 8 + l * 2;
    const int S = 128 >> l;
    const float Sf = (float)S;
    const float rx = rp[0] * Sf - 0.5f;
    const float ry = rp[1] * Sf - 0.5f;
#pragma unroll
    for (int p = 0; p < 4; p++) {
      const int idx = l * 4 + p;
      const float x = rx + off[p * 2 + 0];
      const float y = ry + off[p * 2 + 1];
      const float aw = w[idx] * inv;
      const float x0f = floorf(x), y0f = floorf(y);
      const int x0 = (int)x0f, y0 = (int)y0f;
      const float fx = x - x0f, fy = y - y0f;
      const bool xin0 = (x0 >= 0) & (x0 < S), xin1 = (x0 + 1 >= 0) & (x0 + 1 < S);
      const bool yin0 = (y0 >= 0) & (y0 < S), yin1 = (y0 + 1 >= 0) & (y0 + 1 < S);
      const int xc0 = min(max(x0, 0), S - 1), xc1 = min(max(x0 + 1, 0), S - 1);
      const int yc0 = min(max(y0, 0), S - 1), yc1 = min(max(y0 + 1, 0), S - 1);
      sW[g][h][idx] = make_float4(aw * (1.f - fx) * (1.f - fy) * (float)(xin0 & yin0),
                                  aw * fx * (1.f - fy)         * (float)(xin1 & yin0),
                                  aw * (1.f - fx) * fy         * (float)(xin0 & yin1),
                                  aw * fx * fy                 * (float)(xin1 & yin1));
      // 64B per token-head row in valbH
      sI[g][h][idx] = make_int4((yc0 * S + xc0) << 6, (yc0 * S + xc1) << 6,
                                (yc1 * S + xc0) << 6, (yc1 * S + xc1) << 6);
    }
  }
  __syncthreads();

  const int g = t >> 5, h = (t >> 2) & 7, dc = t & 3;
  const int tok = tok0 + g;
  const int b = tok / LQN;
  f32x2 acc[4] = {};
  const int ST[4] = {0, 16384, 20480, 21504};
#pragma unroll
  for (int l = 0; l < 4; l++) {
    const char* vbc = (const char*)(valbH +
        ((size_t)h * TOKS + (size_t)b * LQN + ST[l]) * 32 + dc * 8);
#pragma unroll
    for (int p = 0; p < 4; p++) {
      float4 W4 = sW[g][h][l * 4 + p];
      int4   I4 = sI[g][h][l * 4 + p];
      uint4 v00 = *(const uint4*)(vbc + I4.x);
      uint4 v10 = *(const uint4*)(vbc + I4.y);
      uint4 v01 = *(const uint4*)(vbc + I4.z);
      uint4 v11 = *(const uint4*)(vbc + I4.w);
      fma8(v00, W4.x, acc);
      fma8(v10, W4.y, acc);
      fma8(v01, W4.z, acc);
      fma8(v11, W4.w, acc);
    }
  }
  unsigned o[4];
#pragma unroll
  for (int i = 0; i < 4; i++)
    o[i] = (unsigned)f2bf(acc[i].x) | ((unsigned)f2bf(acc[i].y) << 16);
  *(uint4*)(outb + (size_t)tok * 256 + h * 32 + dc * 8) = make_uint4(o[0], o[1], o[2], o[3]);
}

extern "C" void kernel_launch(void* const* d_in, const int* in_sizes, int n_in,
                              void* d_out, int out_size, void* d_ws, size_t ws_size,
                              hipStream_t stream) {
  (void)in_sizes; (void)n_in; (void)out_size; (void)ws_size;
  const float* src    = (const float*)d_in[0];
  const float* pos    = (const float*)d_in[1];
  const float* refp   = (const float*)d_in[2];
  const float* W_off  = (const float*)d_in[3];
  const float* b_off  = (const float*)d_in[4];
  const float* W_attn = (const float*)d_in[5];
  const float* b_attn = (const float*)d_in[6];
  const float* W_val  = (const float*)d_in[7];
  const float* b_val  = (const float*)d_in[8];
  const float* W_out  = (const float*)d_in[9];
  const float* b_out  = (const float*)d_in[10];
  const float* ln1_g  = (const float*)d_in[11];
  const float* ln1_b  = (const float*)d_in[12];
  const float* W1     = (const float*)d_in[13];
  const float* b1     = (const float*)d_in[14];
  const float* W2     = (const float*)d_in[15];
  const float* b2     = (const float*)d_in[16];
  const float* ln2_g  = (const float*)d_in[17];
  const float* ln2_b  = (const float*)d_in[18];

  char* ws = (char*)d_ws;
  unsigned short* Wt_val = (unsigned short*)ws;          // 65536
  unsigned short* Wt_oa  = Wt_val + 65536;               // 98304
  unsigned short* Wt_out = Wt_oa + 98304;                // 65536
  unsigned short* Wt_1   = Wt_out + 65536;               // 262144
  unsigned short* Wt_2   = Wt_1 + 262144;                // 262144
  float*          b_oa   = (float*)(Wt_2 + 262144);      // 384
  const size_t WPOOL = 2u * 1024 * 1024;

  const size_t SZ_bf = (size_t)TOKS * 256 * 2;           // 22.3 MB
  const size_t SZ_oa = (size_t)TOKS * 384 * 2;           // 33.4 MB

  unsigned short* srcb  = (unsigned short*)(ws + WPOOL);
  unsigned short* qb    = (unsigned short*)(ws + WPOOL + SZ_bf);
  unsigned short* valb  = (unsigned short*)(ws + WPOOL + 2 * SZ_bf);
  unsigned short* oab   = (unsigned short*)(ws + WPOOL + 3 * SZ_bf);
  unsigned short* valbH = (unsigned short*)(ws + WPOOL + 3 * SZ_bf + SZ_oa);
  // alias (lifetime-disjoint):
  unsigned short* attnoutb = qb;     // deform out; qb dead after proj

  // 1. prep + LDS-tiled weight transposes + bias concat
  prewt_kernel<<<11617, 256, 0, stream>>>(src, pos, srcb, qb,
                                          W_val, W_off, W_attn, W_out, W1, W2, b_off, b_attn,
                                          Wt_val, Wt_oa, Wt_out, Wt_1, Wt_2, b_oa);

  // 2. merged projections: value (N=256) + off/attn (N=384)
  proj_kernel<<<dim3(340, 5), 256, 0, stream>>>(srcb, qb, Wt_val, Wt_oa, b_val, b_oa,
                                                valb, oab);

  // 2b. head-major relayout of values (enables 128B-line corner pairing)
  vrelay_kernel<<<TOKS / 32, 256, 0, stream>>>(valb, valbH);

  // 3. deformable attention (8 tokens/block, XCD-swizzled) over valbH
  deform_kernel<<<TOKS / 8, 256, 0, stream>>>(valbH, oab, refp, attnoutb);

  // 4. fused tail: out-proj + res(src) + LN1 + FFN + res(h) + LN2 -> d_out (f32)
  fused_tail_kernel<<<680, 256, 0, stream>>>(attnoutb, Wt_out, b_out, srcb, ln1_g, ln1_b,
                                             Wt_1, Wt_2, b1, b2, ln2_g, ln2_b,
                                             (float*)d_out);
}

// Round 11
// 433.897 us; speedup vs baseline: 1.0092x; 1.0092x over previous
//
#include <hip/hip_runtime.h>

typedef __bf16 bf16x8 __attribute__((ext_vector_type(8)));
typedef float f32x4 __attribute__((ext_vector_type(4)));
typedef float f32x2 __attribute__((ext_vector_type(2)));

static constexpr int TOKS = 43520;   // B * LQ
static constexpr int LQN  = 21760;

__device__ __forceinline__ unsigned short f2bf(float f) {
  union { float f; unsigned u; } v; v.f = f;
  return (unsigned short)((v.u + 0x7fffu + ((v.u >> 16) & 1u)) >> 16);
}
__device__ __forceinline__ float bf2f(unsigned short b) {
  union { unsigned u; float f; } v; v.u = ((unsigned)b) << 16; return v.f;
}
__device__ __forceinline__ ushort4 c4(float4 v) {
  return make_ushort4(f2bf(v.x), f2bf(v.y), f2bf(v.z), f2bf(v.w));
}
__device__ __forceinline__ float4 add4(float4 a, float4 b) {
  return make_float4(a.x + b.x, a.y + b.y, a.z + b.z, a.w + b.w);
}

// ---- weights-only prep: LDS-tiled transpose + bias concat (737 blocks, ~8 us)
__global__ __launch_bounds__(256) void prewt_kernel(
    const float* __restrict__ W_val, const float* __restrict__ W_off,
    const float* __restrict__ W_attn, const float* __restrict__ W_out,
    const float* __restrict__ W1, const float* __restrict__ W2,
    const float* __restrict__ b_off, const float* __restrict__ b_attn,
    unsigned short* __restrict__ Wt_val, unsigned short* __restrict__ Wt_oa,
    unsigned short* __restrict__ Wt_out,
    unsigned short* __restrict__ Wt_1, unsigned short* __restrict__ Wt_2,
    float* __restrict__ b_oa) {
  const int bid = blockIdx.x;
  const int t = threadIdx.x;
  if (bid == 736) {                    // bias concat
    b_oa[t] = b_off[t];
    if (t < 128) b_oa[256 + t] = b_attn[t];
    return;
  }
  // ---- 32x32 tiled transpose: W [Kd][Nd] f32 -> Wt [Nd][Kd] bf16
  int tid = bid;                       // 0..735
  const float* W; unsigned short* Wt; int Kd, Nd, nshn;
  if (tid < 64)        {            W = W_val;  Wt = Wt_val;         Kd = 256;  Nd = 256;  nshn = 3; }
  else if (tid < 128)  { tid -= 64; W = W_off;  Wt = Wt_oa;          Kd = 256;  Nd = 256;  nshn = 3; }
  else if (tid < 160)  { tid -= 128;W = W_attn; Wt = Wt_oa + 65536;  Kd = 256;  Nd = 128;  nshn = 2; }
  else if (tid < 224)  { tid -= 160;W = W_out;  Wt = Wt_out;         Kd = 256;  Nd = 256;  nshn = 3; }
  else if (tid < 480)  { tid -= 224;W = W1;     Wt = Wt_1;           Kd = 256;  Nd = 1024; nshn = 5; }
  else                 { tid -= 480;W = W2;     Wt = Wt_2;           Kd = 1024; Nd = 256;  nshn = 3; }
  const int k0 = (tid >> nshn) * 32;
  const int n0 = (tid & ((1 << nshn) - 1)) * 32;
  __shared__ float tileT[32][33];
  {
    const int kl = t >> 3, nc = (t & 7) * 4;
    float4 v = *(const float4*)&W[(size_t)(k0 + kl) * Nd + n0 + nc];
    tileT[nc + 0][kl] = v.x; tileT[nc + 1][kl] = v.y;
    tileT[nc + 2][kl] = v.z; tileT[nc + 3][kl] = v.w;
  }
  __syncthreads();
  {
    const int nl = t >> 3, kc = (t & 7) * 4;
    ushort4 o = make_ushort4(f2bf(tileT[nl][kc + 0]), f2bf(tileT[nl][kc + 1]),
                             f2bf(tileT[nl][kc + 2]), f2bf(tileT[nl][kc + 3]));
    *(ushort4*)&Wt[(size_t)(n0 + nl) * Kd + k0 + kc] = o;
  }
}

// ---- proj GEMM body: A staged from f32 (src [+pos]) with on-the-fly f2bf
// (bit-identical to staging from a pre-converted bf16 buffer). K=256.
// WRITESRC blocks also emit srcb (bf16) as a staging byproduct.
template <bool ADDPOS, bool WRITESRC>
__device__ __forceinline__ void proj_body(unsigned short* __restrict__ As,
                                          unsigned short* __restrict__ Bs,
                                          const float* __restrict__ A0,
                                          const float* __restrict__ A1,
                                          const unsigned short* __restrict__ Bt,
                                          const float* __restrict__ bias,
                                          unsigned short* __restrict__ Cp,
                                          unsigned short* __restrict__ srcb_out,
                                          int N, int bm, int bnw) {
  const int t = threadIdx.x;
  const int wave = t >> 6, lane = t & 63;
  const int wm = (wave & 1) << 6, wn = (wave >> 1) << 6;
  const int lr = lane & 15, lq = lane >> 4;
  const int row0 = t >> 2, cb0 = (t & 3) << 3;
  f32x4 acc[4][4] = {};
  const size_t arow = (size_t)(bm * 128 + row0) * 256 + cb0;
  const float* ga0 = A0 + arow;
  const float* ga1 = A0 + arow + (size_t)64 * 256;
  const float* gp0 = A1 + arow;
  const float* gp1 = A1 + arow + (size_t)64 * 256;
  const unsigned short* gb = Bt + (size_t)(bnw * 128 + row0) * 256 + cb0;
  const size_t gs = (size_t)64 * 256;

  float4 fa0 = *(const float4*)ga0, fa1 = *(const float4*)(ga0 + 4);
  float4 fa2 = *(const float4*)ga1, fa3 = *(const float4*)(ga1 + 4);
  float4 fp0, fp1, fp2, fp3;
  if (ADDPOS) {
    fp0 = *(const float4*)gp0; fp1 = *(const float4*)(gp0 + 4);
    fp2 = *(const float4*)gp1; fp3 = *(const float4*)(gp1 + 4);
  }
  uint4 pb0 = *(const uint4*)gb;
  uint4 pb1 = *(const uint4*)(gb + gs);
  int p = 0;
#pragma unroll 1
  for (int k0 = 0; k0 < 256; k0 += 32) {
    float4 v0 = fa0, v1 = fa1, v2 = fa2, v3 = fa3;
    if (ADDPOS) { v0 = add4(v0, fp0); v1 = add4(v1, fp1); v2 = add4(v2, fp2); v3 = add4(v3, fp3); }
    ushort4 u0 = c4(v0), u1 = c4(v1), u2 = c4(v2), u3 = c4(v3);
    unsigned short* Ab = As + p * 5120;
    unsigned short* Bb = Bs + p * 5120;
    *(ushort4*)&Ab[row0 * 40 + cb0] = u0;
    *(ushort4*)&Ab[row0 * 40 + cb0 + 4] = u1;
    *(ushort4*)&Ab[(row0 + 64) * 40 + cb0] = u2;
    *(ushort4*)&Ab[(row0 + 64) * 40 + cb0 + 4] = u3;
    *(uint4*)&Bb[row0 * 40 + cb0] = pb0;
    *(uint4*)&Bb[(row0 + 64) * 40 + cb0] = pb1;
    if (WRITESRC) {
      *(ushort4*)&srcb_out[arow + k0] = u0;
      *(ushort4*)&srcb_out[arow + k0 + 4] = u1;
      *(ushort4*)&srcb_out[arow + (size_t)64 * 256 + k0] = u2;
      *(ushort4*)&srcb_out[arow + (size_t)64 * 256 + k0 + 4] = u3;
    }
    __syncthreads();
    if (k0 + 32 < 256) {
      fa0 = *(const float4*)(ga0 + k0 + 32);
      fa1 = *(const float4*)(ga0 + k0 + 36);
      fa2 = *(const float4*)(ga1 + k0 + 32);
      fa3 = *(const float4*)(ga1 + k0 + 36);
      if (ADDPOS) {
        fp0 = *(const float4*)(gp0 + k0 + 32);
        fp1 = *(const float4*)(gp0 + k0 + 36);
        fp2 = *(const float4*)(gp1 + k0 + 32);
        fp3 = *(const float4*)(gp1 + k0 + 36);
      }
      pb0 = *(const uint4*)(gb + k0 + 32);
      pb1 = *(const uint4*)(gb + gs + k0 + 32);
    }
    bf16x8 af[4], bfr[4];
#pragma unroll
    for (int i = 0; i < 4; i++) af[i] = *(const bf16x8*)&Ab[(wm + i * 16 + lr) * 40 + lq * 8];
#pragma unroll
    for (int j = 0; j < 4; j++) bfr[j] = *(const bf16x8*)&Bb[(wn + j * 16 + lr) * 40 + lq * 8];
#pragma unroll
    for (int i = 0; i < 4; i++)
#pragma unroll
      for (int j = 0; j < 4; j++)
        acc[i][j] = __builtin_amdgcn_mfma_f32_16x16x32_bf16(af[i], bfr[j], acc[i][j], 0, 0, 0);
    p ^= 1;
  }
  const int rb = bm * 128 + wm + lq * 4;
  const int cbase = bnw * 128 + wn + lr;
#pragma unroll
  for (int j = 0; j < 4; j++) {
    const int col = cbase + j * 16;
    const float bv = bias[col];
#pragma unroll
    for (int i = 0; i < 4; i++)
#pragma unroll
      for (int r = 0; r < 4; r++)
        Cp[(size_t)(rb + i * 16 + r) * N + col] = f2bf(acc[i][j][r] + bv);
  }
}

__global__ __launch_bounds__(256) void proj_kernel(
    const float* __restrict__ src, const float* __restrict__ pos,
    const unsigned short* __restrict__ Wt_val, const unsigned short* __restrict__ Wt_oa,
    const float* __restrict__ b_val, const float* __restrict__ b_oa,
    unsigned short* __restrict__ valb, unsigned short* __restrict__ oab,
    unsigned short* __restrict__ srcb) {
  __shared__ unsigned short As[2 * 5120];
  __shared__ unsigned short Bs[2 * 5120];
  const int bn = blockIdx.y;
  if (bn == 0)
    proj_body<false, true>(As, Bs, src, src, Wt_val, b_val, valb, srcb, 256, blockIdx.x, 0);
  else if (bn == 1)
    proj_body<false, false>(As, Bs, src, src, Wt_val, b_val, valb, nullptr, 256, blockIdx.x, 1);
  else
    proj_body<true, false>(As, Bs, src, pos, Wt_oa, b_oa, oab, nullptr, 384, blockIdx.x, bn - 2);
}

// ---- fused tail (R8-proven): out-proj + res(src) + LN1 + FFN + res(h) + LN2.
__global__ __launch_bounds__(256, 3) void fused_tail_kernel(
    const unsigned short* __restrict__ attn,
    const unsigned short* __restrict__ Wot,
    const float* __restrict__ b_out,
    const unsigned short* __restrict__ srcres,
    const float* __restrict__ g1, const float* __restrict__ be1,
    const unsigned short* __restrict__ W1t,
    const unsigned short* __restrict__ W2t,
    const float* __restrict__ b1, const float* __restrict__ b2,
    const float* __restrict__ g2, const float* __restrict__ be2,
    float* __restrict__ out) {
  __shared__ unsigned short Ah[64 * 264];
  __shared__ unsigned short Hc[64 * 136];
  __shared__ float red[2][4][64];
  const int t = threadIdx.x;
  const int w = t >> 6, lane = t & 63;
  const int lr = lane & 15, lq = lane >> 4;
  const size_t rowbase = (size_t)blockIdx.x * 64;

  {
    const uint4* gsrc = (const uint4*)(attn + rowbase * 256);
#pragma unroll
    for (int u = 0; u < 8; u++) {
      const int idx = u * 256 + t;
      const int row = idx >> 5, c8 = idx & 31;
      *(uint4*)&Ah[row * 264 + c8 * 8] = gsrc[idx];
    }
  }
  __syncthreads();

  // ---- GEMM0: out-proj (K=256), depth-2 weight prefetch, full unroll
  f32x4 acc0[4][4] = {};
  {
    const size_t wb = (size_t)(w * 64 + lr) * 256 + lq * 8;
    bf16x8 wf0[2][4];
#pragma unroll
    for (int d = 0; d < 2; d++)
#pragma unroll
      for (int j = 0; j < 4; j++)
        wf0[d][j] = *(const bf16x8*)&Wot[wb + (size_t)j * 4096 + d * 32];
#pragma unroll
    for (int ks = 0; ks < 8; ks++) {
      bf16x8 c0 = wf0[ks & 1][0], c1 = wf0[ks & 1][1];
      bf16x8 c2 = wf0[ks & 1][2], c3 = wf0[ks & 1][3];
      if (ks + 2 < 8) {
#pragma unroll
        for (int j = 0; j < 4; j++)
          wf0[ks & 1][j] = *(const bf16x8*)&Wot[wb + (size_t)j * 4096 + (ks + 2) * 32];
      }
      bf16x8 af[4];
#pragma unroll
      for (int i = 0; i < 4; i++)
        af[i] = *(const bf16x8*)&Ah[(i * 16 + lr) * 264 + ks * 32 + lq * 8];
#pragma unroll
      for (int i = 0; i < 4; i++) {
        acc0[i][0] = __builtin_amdgcn_mfma_f32_16x16x32_bf16(af[i], c0, acc0[i][0], 0, 0, 0);
        acc0[i][1] = __builtin_amdgcn_mfma_f32_16x16x32_bf16(af[i], c1, acc0[i][1], 0, 0, 0);
        acc0[i][2] = __builtin_amdgcn_mfma_f32_16x16x32_bf16(af[i], c2, acc0[i][2], 0, 0, 0);
        acc0[i][3] = __builtin_amdgcn_mfma_f32_16x16x32_bf16(af[i], c3, acc0[i][3], 0, 0, 0);
      }
    }
  }
  // ---- epilogue0: +b_out +res(src) ; LN1 ; h -> Ah (bf16, in place)
  {
    float vsum[4][4], vsq[4][4];
#pragma unroll
    for (int i = 0; i < 4; i++)
#pragma unroll
      for (int r = 0; r < 4; r++) { vsum[i][r] = 0.f; vsq[i][r] = 0.f; }
#pragma unroll
    for (int j = 0; j < 4; j++) {
      const int col = w * 64 + j * 16 + lr;
      const float bv = b_out[col];
#pragma unroll
      for (int i = 0; i < 4; i++)
#pragma unroll
        for (int r = 0; r < 4; r++) {
          const int row = i * 16 + lq * 4 + r;
          float v = acc0[i][j][r] + bv + bf2f(srcres[(rowbase + row) * 256 + col]);
          acc0[i][j][r] = v;
          vsum[i][r] += v;
          vsq[i][r]  += v * v;
        }
    }
#pragma unroll
    for (int m = 1; m <= 8; m <<= 1)
#pragma unroll
      for (int i = 0; i < 4; i++)
#pragma unroll
        for (int r = 0; r < 4; r++) {
          vsum[i][r] += __shfl_xor(vsum[i][r], m, 64);
          vsq[i][r]  += __shfl_xor(vsq[i][r],  m, 64);
        }
    if (lr == 0) {
#pragma unroll
      for (int i = 0; i < 4; i++)
#pragma unroll
        for (int r = 0; r < 4; r++) {
          const int row = i * 16 + lq * 4 + r;
          red[0][w][row] = vsum[i][r];
          red[1][w][row] = vsq[i][r];
        }
    }
    __syncthreads();
    float mu[4][4], rstd[4][4];
#pragma unroll
    for (int i = 0; i < 4; i++)
#pragma unroll
      for (int r = 0; r < 4; r++) {
        const int row = i * 16 + lq * 4 + r;
        const float ts = red[0][0][row] + red[0][1][row] + red[0][2][row] + red[0][3][row];
        const float tq = red[1][0][row] + red[1][1][row] + red[1][2][row] + red[1][3][row];
        const float m_ = ts * (1.f / 256.f);
        mu[i][r] = m_;
        rstd[i][r] = rsqrtf(tq * (1.f / 256.f) - m_ * m_ + 1e-5f);
      }
#pragma unroll
    for (int j = 0; j < 4; j++) {
      const int col = w * 64 + j * 16 + lr;
      const float gg = g1[col], bb = be1[col];
#pragma unroll
      for (int i = 0; i < 4; i++)
#pragma unroll
        for (int r = 0; r < 4; r++) {
          const int row = i * 16 + lq * 4 + r;
          const float y = (acc0[i][j][r] - mu[i][r]) * rstd[i][r] * gg + bb;
          Ah[row * 264 + col] = f2bf(y);
        }
    }
  }
  __syncthreads();

  // ---- FFN: 8 chunks of 128 hidden cols; deep weight prefetch
  f32x4 acc2[4][4] = {};
  const int c1base = w * 32;
#pragma unroll 1
  for (int c2 = 0; c2 < 8; c2++) {
    f32x4 acc1[4][2] = {};
    const size_t w1r0 = (size_t)(c2 * 128 + c1base + lr) * 256 + lq * 8;
    const size_t w1r1 = w1r0 + (size_t)16 * 256;
    bf16x8 wf[4][2];
#pragma unroll
    for (int d = 0; d < 4; d++) {
      wf[d][0] = *(const bf16x8*)&W1t[w1r0 + d * 32];
      wf[d][1] = *(const bf16x8*)&W1t[w1r1 + d * 32];
    }
#pragma unroll
    for (int ks = 0; ks < 8; ks++) {
      bf16x8 b0 = wf[ks & 3][0], b1v = wf[ks & 3][1];
      if (ks + 4 < 8) {
        wf[ks & 3][0] = *(const bf16x8*)&W1t[w1r0 + (ks + 4) * 32];
        wf[ks & 3][1] = *(const bf16x8*)&W1t[w1r1 + (ks + 4) * 32];
      }
      bf16x8 af[4];
#pragma unroll
      for (int i = 0; i < 4; i++)
        af[i] = *(const bf16x8*)&Ah[(i * 16 + lr) * 264 + ks * 32 + lq * 8];
#pragma unroll
      for (int i = 0; i < 4; i++) {
        acc1[i][0] = __builtin_amdgcn_mfma_f32_16x16x32_bf16(af[i], b0,  acc1[i][0], 0, 0, 0);
        acc1[i][1] = __builtin_amdgcn_mfma_f32_16x16x32_bf16(af[i], b1v, acc1[i][1], 0, 0, 0);
      }
    }
    __syncthreads();
#pragma unroll
    for (int j = 0; j < 2; j++) {
      const int colc = c1base + j * 16 + lr;
      const float bv = b1[c2 * 128 + colc];
#pragma unroll
      for (int i = 0; i < 4; i++)
#pragma unroll
        for (int r = 0; r < 4; r++)
          Hc[(i * 16 + lq * 4 + r) * 136 + colc] = f2bf(fmaxf(acc1[i][j][r] + bv, 0.f));
    }
    __syncthreads();
    const size_t w2b = (size_t)(w * 64 + lr) * 1024 + c2 * 128 + lq * 8;
    bf16x8 wg[2][4];
#pragma unroll
    for (int d = 0; d < 2; d++)
#pragma unroll
      for (int j = 0; j < 4; j++)
        wg[d][j] = *(const bf16x8*)&W2t[w2b + (size_t)j * 16384 + d * 32];
#pragma unroll
    for (int ks = 0; ks < 4; ks++) {
      bf16x8 c0 = wg[ks & 1][0], c1 = wg[ks & 1][1];
      bf16x8 cc2 = wg[ks & 1][2], c3 = wg[ks & 1][3];
      if (ks + 2 < 4) {
#pragma unroll
        for (int j = 0; j < 4; j++)
          wg[ks & 1][j] = *(const bf16x8*)&W2t[w2b + (size_t)j * 16384 + (ks + 2) * 32];
      }
      bf16x8 af2[4];
#pragma unroll
      for (int i = 0; i < 4; i++)
        af2[i] = *(const bf16x8*)&Hc[(i * 16 + lr) * 136 + ks * 32 + lq * 8];
#pragma unroll
      for (int i = 0; i < 4; i++) {
        acc2[i][0] = __builtin_amdgcn_mfma_f32_16x16x32_bf16(af2[i], c0,  acc2[i][0], 0, 0, 0);
        acc2[i][1] = __builtin_amdgcn_mfma_f32_16x16x32_bf16(af2[i], c1,  acc2[i][1], 0, 0, 0);
        acc2[i][2] = __builtin_amdgcn_mfma_f32_16x16x32_bf16(af2[i], cc2, acc2[i][2], 0, 0, 0);
        acc2[i][3] = __builtin_amdgcn_mfma_f32_16x16x32_bf16(af2[i], c3,  acc2[i][3], 0, 0, 0);
      }
    }
  }
  // ---- epilogue2: +b2 +res(h from Ah) ; LN2 ; f32 out
  float vsum[4][4], vsq[4][4];
#pragma unroll
  for (int i = 0; i < 4; i++)
#pragma unroll
    for (int r = 0; r < 4; r++) { vsum[i][r] = 0.f; vsq[i][r] = 0.f; }
#pragma unroll
  for (int j = 0; j < 4; j++) {
    const int col = w * 64 + j * 16 + lr;
    const float bv = b2[col];
#pragma unroll
    for (int i = 0; i < 4; i++)
#pragma unroll
      for (int r = 0; r < 4; r++) {
        const int row = i * 16 + lq * 4 + r;
        float v = acc2[i][j][r] + bv + bf2f(Ah[row * 264 + col]);
        acc2[i][j][r] = v;
        vsum[i][r] += v;
        vsq[i][r]  += v * v;
      }
  }
#pragma unroll
  for (int m = 1; m <= 8; m <<= 1)
#pragma unroll
    for (int i = 0; i < 4; i++)
#pragma unroll
      for (int r = 0; r < 4; r++) {
        vsum[i][r] += __shfl_xor(vsum[i][r], m, 64);
        vsq[i][r]  += __shfl_xor(vsq[i][r],  m, 64);
      }
  __syncthreads();
  if (lr == 0) {
#pragma unroll
    for (int i = 0; i < 4; i++)
#pragma unroll
      for (int r = 0; r < 4; r++) {
        const int row = i * 16 + lq * 4 + r;
        red[0][w][row] = vsum[i][r];
        red[1][w][row] = vsq[i][r];
      }
  }
  __syncthreads();
  float mu[4][4], rstd[4][4];
#pragma unroll
  for (int i = 0; i < 4; i++)
#pragma unroll
    for (int r = 0; r < 4; r++) {
      const int row = i * 16 + lq * 4 + r;
      const float ts = red[0][0][row] + red[0][1][row] + red[0][2][row] + red[0][3][row];
      const float tq = red[1][0][row] + red[1][1][row] + red[1][2][row] + red[1][3][row];
      const float m_ = ts * (1.f / 256.f);
      mu[i][r] = m_;
      rstd[i][r] = rsqrtf(tq * (1.f / 256.f) - m_ * m_ + 1e-5f);
    }
#pragma unroll
  for (int j = 0; j < 4; j++) {
    const int col = w * 64 + j * 16 + lr;
    const float gg = g2[col], bb = be2[col];
#pragma unroll
    for (int i = 0; i < 4; i++)
#pragma unroll
      for (int r = 0; r < 4; r++) {
        const int row = i * 16 + lq * 4 + r;
        out[(rowbase + row) * 256 + col] = (acc2[i][j][r] - mu[i][r]) * rstd[i][r] * gg + bb;
      }
  }
}

// ---- bf16x8 (uint4) fused unpack + PACKED FMA (v_pk_fma_f32) into f32x2 acc
__device__ __forceinline__ void fma8(uint4 v, float w, f32x2* a) {
  const unsigned uu[4] = {v.x, v.y, v.z, v.w};
  const f32x2 w2 = {w, w};
#pragma unroll
  for (int i = 0; i < 4; i++) {
    union { unsigned u; float f; } lo, hi;
    lo.u = uu[i] << 16;
    hi.u = uu[i] & 0xffff0000u;
    f32x2 val = {lo.f, hi.f};
    a[i] += w2 * val;
  }
}

// ---- deformable attention (R8): two-phase, int4 byte-offset tables, XCD swizzle
__global__ __launch_bounds__(256) void deform_kernel(const unsigned short* __restrict__ valb,
                                                     const unsigned short* __restrict__ oab,
                                                     const float* __restrict__ refp,
                                                     unsigned short* __restrict__ outb) {
  __shared__ float4 sW[8][8][17];
  __shared__ int4   sI[8][8][17];
  const int t = threadIdx.x;
  const int bid = blockIdx.x;
  const int nb = (bid & 7) * 680 + (bid >> 3);
  const int tok0 = nb * 8;

  {
    const int g = t >> 5, h = (t >> 2) & 7, l = t & 3;
    const int tok = tok0 + g;
    const unsigned short* lg = oab + (size_t)tok * 384 + 256 + h * 16;
    uint4 lv0 = ((const uint4*)lg)[0];
    uint4 lv1 = ((const uint4*)lg)[1];
    const unsigned lw[8] = {lv0.x, lv0.y, lv0.z, lv0.w, lv1.x, lv1.y, lv1.z, lv1.w};
    float w[16];
#pragma unroll
    for (int i = 0; i < 8; i++) {
      union { unsigned u; float f; } lo, hi;
      lo.u = lw[i] << 16; hi.u = lw[i] & 0xffff0000u;
      w[2 * i] = lo.f; w[2 * i + 1] = hi.f;
    }
    float mx = -1e30f;
#pragma unroll
    for (int i = 0; i < 16; i++) mx = fmaxf(mx, w[i]);
    float s = 0.f;
#pragma unroll
    for (int i = 0; i < 16; i++) { w[i] = __expf(w[i] - mx); s += w[i]; }
    const float inv = 1.f / s;
    uint4 ov = *(const uint4*)(oab + (size_t)tok * 384 + h * 32 + l * 8);
    const unsigned owv[4] = {ov.x, ov.y, ov.z, ov.w};
    float off[8];
#pragma unroll
    for (int i = 0; i < 4; i++) {
      union { unsigned u; float f; } lo, hi;
      lo.u = owv[i] << 16; hi.u = owv[i] & 0xffff0000u;
      off[2 * i] = lo.f; off[2 * i + 1] = hi.f;
    }
    const float* rp = refp + (size_t)tok * 8 + l * 2;
    const int S = 128 >> l;
    const float Sf = (float)S;
    const float rx = rp[0] * Sf - 0.5f;
    const float ry = rp[1] * Sf - 0.5f;
#pragma unroll
    for (int p = 0; p < 4; p++) {
      const int idx = l * 4 + p;
      const float x = rx + off[p * 2 + 0];
      const float y = ry + off[p * 2 + 1];
      const float aw = w[idx] * inv;
      const float x0f = floorf(x), y0f = floorf(y);
      const int x0 = (int)x0f, y0 = (int)y0f;
      const float fx = x - x0f, fy = y - y0f;
      const bool xin0 = (x0 >= 0) & (x0 < S), xin1 = (x0 + 1 >= 0) & (x0 + 1 < S);
      const bool yin0 = (y0 >= 0) & (y0 < S), yin1 = (y0 + 1 >= 0) & (y0 + 1 < S);
      const int xc0 = min(max(x0, 0), S - 1), xc1 = min(max(x0 + 1, 0), S - 1);
      const int yc0 = min(max(y0, 0), S - 1), yc1 = min(max(y0 + 1, 0), S - 1);
      sW[g][h][idx] = make_float4(aw * (1.f - fx) * (1.f - fy) * (float)(xin0 & yin0),
                                  aw * fx * (1.f - fy)         * (float)(xin1 & yin0),
                                  aw * (1.f - fx) * fy         * (float)(xin0 & yin1),
                                  aw * fx * fy                 * (float)(xin1 & yin1));
      sI[g][h][idx] = make_int4((yc0 * S + xc0) << 9, (yc0 * S + xc1) << 9,
                                (yc1 * S + xc0) << 9, (yc1 * S + xc1) << 9);
    }
  }
  __syncthreads();

  const int g = t >> 5, h = (t >> 2) & 7, dc = t & 3;
  const int tok = tok0 + g;
  const int b = tok / LQN;
  f32x2 acc[4] = {};
  const int ST[4] = {0, 16384, 20480, 21504};
#pragma unroll
  for (int l = 0; l < 4; l++) {
    const char* vbc = (const char*)(valb + ((size_t)(b * LQN + ST[l])) * 256 + h * 32 + dc * 8);
#pragma unroll
    for (int p = 0; p < 4; p++) {
      float4 W4 = sW[g][h][l * 4 + p];
      int4   I4 = sI[g][h][l * 4 + p];
      uint4 v00 = *(const uint4*)(vbc + I4.x);
      uint4 v10 = *(const uint4*)(vbc + I4.y);
      uint4 v01 = *(const uint4*)(vbc + I4.z);
      uint4 v11 = *(const uint4*)(vbc + I4.w);
      fma8(v00, W4.x, acc);
      fma8(v10, W4.y, acc);
      fma8(v01, W4.z, acc);
      fma8(v11, W4.w, acc);
    }
  }
  unsigned o[4];
#pragma unroll
  for (int i = 0; i < 4; i++)
    o[i] = (unsigned)f2bf(acc[i].x) | ((unsigned)f2bf(acc[i].y) << 16);
  *(uint4*)(outb + (size_t)tok * 256 + h * 32 + dc * 8) = make_uint4(o[0], o[1], o[2], o[3]);
}

extern "C" void kernel_launch(void* const* d_in, const int* in_sizes, int n_in,
                              void* d_out, int out_size, void* d_ws, size_t ws_size,
                              hipStream_t stream) {
  (void)in_sizes; (void)n_in; (void)out_size; (void)ws_size;
  const float* src    = (const float*)d_in[0];
  const float* pos    = (const float*)d_in[1];
  const float* refp   = (const float*)d_in[2];
  const float* W_off  = (const float*)d_in[3];
  const float* b_off  = (const float*)d_in[4];
  const float* W_attn = (const float*)d_in[5];
  const float* b_attn = (const float*)d_in[6];
  const float* W_val  = (const float*)d_in[7];
  const float* b_val  = (const float*)d_in[8];
  const float* W_out  = (const float*)d_in[9];
  const float* b_out  = (const float*)d_in[10];
  const float* ln1_g  = (const float*)d_in[11];
  const float* ln1_b  = (const float*)d_in[12];
  const float* W1     = (const float*)d_in[13];
  const float* b1     = (const float*)d_in[14];
  const float* W2     = (const float*)d_in[15];
  const float* b2     = (const float*)d_in[16];
  const float* ln2_g  = (const float*)d_in[17];
  const float* ln2_b  = (const float*)d_in[18];

  char* ws = (char*)d_ws;
  unsigned short* Wt_val = (unsigned short*)ws;          // 65536
  unsigned short* Wt_oa  = Wt_val + 65536;               // 98304
  unsigned short* Wt_out = Wt_oa + 98304;                // 65536
  unsigned short* Wt_1   = Wt_out + 65536;               // 262144
  unsigned short* Wt_2   = Wt_1 + 262144;                // 262144
  float*          b_oa   = (float*)(Wt_2 + 262144);      // 384
  const size_t WPOOL = 2u * 1024 * 1024;

  const size_t SZ_bf = (size_t)TOKS * 256 * 2;           // 22.3 MB

  unsigned short* srcb     = (unsigned short*)(ws + WPOOL);
  unsigned short* attnoutb = (unsigned short*)(ws + WPOOL + SZ_bf);
  unsigned short* valb     = (unsigned short*)(ws + WPOOL + 2 * SZ_bf);
  unsigned short* oab      = (unsigned short*)(ws + WPOOL + 3 * SZ_bf);

  // 1. weight transposes + bias concat (weights only, ~8 us)
  prewt_kernel<<<737, 256, 0, stream>>>(W_val, W_off, W_attn, W_out, W1, W2, b_off, b_attn,
                                        Wt_val, Wt_oa, Wt_out, Wt_1, Wt_2, b_oa);

  // 2. merged projections from f32 src/pos (on-the-fly bf16 convert; bn==0 emits srcb)
  proj_kernel<<<dim3(340, 5), 256, 0, stream>>>(src, pos, Wt_val, Wt_oa, b_val, b_oa,
                                                valb, oab, srcb);

  // 3. deformable attention (8 tokens/block, XCD-swizzled)
  deform_kernel<<<TOKS / 8, 256, 0, stream>>>(valb, oab, refp, attnoutb);

  // 4. fused tail: out-proj + res(src) + LN1 + FFN + res(h) + LN2 -> d_out (f32)
  fused_tail_kernel<<<680, 256, 0, stream>>>(attnoutb, Wt_out, b_out, srcb, ln1_g, ln1_b,
                                             Wt_1, Wt_2, b1, b2, ln2_g, ln2_b,
                                             (float*)d_out);
}

// Round 12
// 428.170 us; speedup vs baseline: 1.0227x; 1.0134x over previous
//
#include <hip/hip_runtime.h>

typedef __bf16 bf16x8 __attribute__((ext_vector_type(8)));
typedef float f32x4 __attribute__((ext_vector_type(4)));
typedef float f32x2 __attribute__((ext_vector_type(2)));

static constexpr int TOKS = 43520;   // B * LQ
static constexpr int LQN  = 21760;

__device__ __forceinline__ unsigned short f2bf(float f) {
  union { float f; unsigned u; } v; v.f = f;
  return (unsigned short)((v.u + 0x7fffu + ((v.u >> 16) & 1u)) >> 16);
}
__device__ __forceinline__ float bf2f(unsigned short b) {
  union { unsigned u; float f; } v; v.u = ((unsigned)b) << 16; return v.f;
}

// ---- fused prep + LDS-tiled weight transpose (coalesced stores) + bias concat
__global__ __launch_bounds__(256) void prewt_kernel(
    const float* __restrict__ src, const float* __restrict__ pos,
    unsigned short* __restrict__ srcb, unsigned short* __restrict__ qb,
    const float* __restrict__ W_val, const float* __restrict__ W_off,
    const float* __restrict__ W_attn, const float* __restrict__ W_out,
    const float* __restrict__ W1, const float* __restrict__ W2,
    const float* __restrict__ b_off, const float* __restrict__ b_attn,
    unsigned short* __restrict__ Wt_val, unsigned short* __restrict__ Wt_oa,
    unsigned short* __restrict__ Wt_out,
    unsigned short* __restrict__ Wt_1, unsigned short* __restrict__ Wt_2,
    float* __restrict__ b_oa) {
  const int bid = blockIdx.x;
  const int t = threadIdx.x;
  if (bid < 10880) {
    int i = bid * 256 + t;
    float4 s = ((const float4*)src)[i], p = ((const float4*)pos)[i];
    ((ushort4*)srcb)[i] = make_ushort4(f2bf(s.x), f2bf(s.y), f2bf(s.z), f2bf(s.w));
    ((ushort4*)qb)[i]   = make_ushort4(f2bf(s.x + p.x), f2bf(s.y + p.y),
                                       f2bf(s.z + p.z), f2bf(s.w + p.w));
    return;
  }
  if (bid == 11616) {                  // bias concat
    b_oa[t] = (t < 256) ? b_off[t] : 0.f;
    if (t >= 256) return;
    if (t < 128) b_oa[256 + t] = b_attn[t];
    return;
  }
  // ---- 32x32 tiled transpose: W [Kd][Nd] f32 -> Wt [Nd][Kd] bf16
  int tid = bid - 10880;               // 0..735
  const float* W; unsigned short* Wt; int Kd, Nd, nshn;
  if (tid < 64)        {            W = W_val;  Wt = Wt_val;         Kd = 256;  Nd = 256;  nshn = 3; }
  else if (tid < 128)  { tid -= 64; W = W_off;  Wt = Wt_oa;          Kd = 256;  Nd = 256;  nshn = 3; }
  else if (tid < 160)  { tid -= 128;W = W_attn; Wt = Wt_oa + 65536;  Kd = 256;  Nd = 128;  nshn = 2; }
  else if (tid < 224)  { tid -= 160;W = W_out;  Wt = Wt_out;         Kd = 256;  Nd = 256;  nshn = 3; }
  else if (tid < 480)  { tid -= 224;W = W1;     Wt = Wt_1;           Kd = 256;  Nd = 1024; nshn = 5; }
  else                 { tid -= 480;W = W2;     Wt = Wt_2;           Kd = 1024; Nd = 256;  nshn = 3; }
  const int k0 = (tid >> nshn) * 32;
  const int n0 = (tid & ((1 << nshn) - 1)) * 32;
  __shared__ float tileT[32][33];
  {
    const int kl = t >> 3, nc = (t & 7) * 4;
    float4 v = *(const float4*)&W[(size_t)(k0 + kl) * Nd + n0 + nc];
    tileT[nc + 0][kl] = v.x; tileT[nc + 1][kl] = v.y;
    tileT[nc + 2][kl] = v.z; tileT[nc + 3][kl] = v.w;
  }
  __syncthreads();
  {
    const int nl = t >> 3, kc = (t & 7) * 4;
    ushort4 o = make_ushort4(f2bf(tileT[nl][kc + 0]), f2bf(tileT[nl][kc + 1]),
                             f2bf(tileT[nl][kc + 2]), f2bf(tileT[nl][kc + 3]));
    *(ushort4*)&Wt[(size_t)(n0 + nl) * Kd + k0 + kc] = o;
  }
}

// ---- R2-proven 128x128 GEMM body: padded LDS, reg staging, ONE barrier per K-iter.
template <int K, int OUTOP>
__device__ __forceinline__ void gemm_body(unsigned short* __restrict__ As,
                                          unsigned short* __restrict__ Bs,
                                          const unsigned short* __restrict__ A,
                                          const unsigned short* __restrict__ Bt,
                                          const float* __restrict__ bias,
                                          const unsigned short* __restrict__ res,
                                          unsigned short* __restrict__ Cp,
                                          int N, int bm, int bn) {
  const int t = threadIdx.x;
  const int wave = t >> 6, lane = t & 63;
  const int wm = (wave & 1) << 6, wn = (wave >> 1) << 6;
  const int lr = lane & 15, lq = lane >> 4;
  const int row0 = t >> 2, cb0 = (t & 3) << 3;
  f32x4 acc[4][4] = {};
  const unsigned short* ga = A  + (size_t)(bm * 128 + row0) * K + cb0;
  const unsigned short* gb = Bt + (size_t)(bn * 128 + row0) * K + cb0;
  const size_t gs = (size_t)64 * K;
  uint4 pa0 = *(const uint4*)ga;
  uint4 pa1 = *(const uint4*)(ga + gs);
  uint4 pb0 = *(const uint4*)gb;
  uint4 pb1 = *(const uint4*)(gb + gs);
  int p = 0;
#pragma unroll 1
  for (int k0 = 0; k0 < K; k0 += 32) {
    unsigned short* Ab = As + p * 5120;
    unsigned short* Bb = Bs + p * 5120;
    *(uint4*)&Ab[row0 * 40 + cb0] = pa0;
    *(uint4*)&Ab[(row0 + 64) * 40 + cb0] = pa1;
    *(uint4*)&Bb[row0 * 40 + cb0] = pb0;
    *(uint4*)&Bb[(row0 + 64) * 40 + cb0] = pb1;
    __syncthreads();
    if (k0 + 32 < K) {
      pa0 = *(const uint4*)(ga + k0 + 32);
      pa1 = *(const uint4*)(ga + gs + k0 + 32);
      pb0 = *(const uint4*)(gb + k0 + 32);
      pb1 = *(const uint4*)(gb + gs + k0 + 32);
    }
    bf16x8 af[4], bfr[4];
#pragma unroll
    for (int i = 0; i < 4; i++) af[i] = *(const bf16x8*)&Ab[(wm + i * 16 + lr) * 40 + lq * 8];
#pragma unroll
    for (int j = 0; j < 4; j++) bfr[j] = *(const bf16x8*)&Bb[(wn + j * 16 + lr) * 40 + lq * 8];
#pragma unroll
    for (int i = 0; i < 4; i++)
#pragma unroll
      for (int j = 0; j < 4; j++)
        acc[i][j] = __builtin_amdgcn_mfma_f32_16x16x32_bf16(af[i], bfr[j], acc[i][j], 0, 0, 0);
    p ^= 1;
  }
  const int rb = bm * 128 + wm + lq * 4;
  const int cbase = bn * 128 + wn + lr;
#pragma unroll
  for (int j = 0; j < 4; j++) {
    const int col = cbase + j * 16;
    const float bv = bias[col];
#pragma unroll
    for (int i = 0; i < 4; i++) {
#pragma unroll
      for (int r = 0; r < 4; r++) {
        float v = acc[i][j][r] + bv;
        size_t o = (size_t)(rb + i * 16 + r) * N + col;
        if (OUTOP == 1) Cp[o] = f2bf(v);
        else if (OUTOP == 2) Cp[o] = f2bf(fmaxf(v, 0.f));
        else Cp[o] = f2bf(v + bf2f(res[o]));
      }
    }
  }
}

__global__ __launch_bounds__(256) void proj_kernel(
    const unsigned short* __restrict__ srcb, const unsigned short* __restrict__ qb,
    const unsigned short* __restrict__ Wt_val, const unsigned short* __restrict__ Wt_oa,
    const float* __restrict__ b_val, const float* __restrict__ b_oa,
    unsigned short* __restrict__ valb, unsigned short* __restrict__ oab) {
  __shared__ unsigned short As[2 * 5120];
  __shared__ unsigned short Bs[2 * 5120];
  const int bn = blockIdx.y;
  if (bn < 2)
    gemm_body<256, 1>(As, Bs, srcb, Wt_val, b_val, nullptr, valb, 256, blockIdx.x, bn);
  else
    gemm_body<256, 1>(As, Bs, qb, Wt_oa, b_oa, nullptr, oab, 384, blockIdx.x, bn - 2);
}

// ---- fused tail (R8-proven): out-proj + res(src) + LN1 + FFN + res(h) + LN2.
__global__ __launch_bounds__(256, 3) void fused_tail_kernel(
    const unsigned short* __restrict__ attn,
    const unsigned short* __restrict__ Wot,
    const float* __restrict__ b_out,
    const unsigned short* __restrict__ srcres,
    const float* __restrict__ g1, const float* __restrict__ be1,
    const unsigned short* __restrict__ W1t,
    const unsigned short* __restrict__ W2t,
    const float* __restrict__ b1, const float* __restrict__ b2,
    const float* __restrict__ g2, const float* __restrict__ be2,
    float* __restrict__ out) {
  __shared__ unsigned short Ah[64 * 264];
  __shared__ unsigned short Hc[64 * 136];
  __shared__ float red[2][4][64];
  const int t = threadIdx.x;
  const int w = t >> 6, lane = t & 63;
  const int lr = lane & 15, lq = lane >> 4;
  const size_t rowbase = (size_t)blockIdx.x * 64;

  {
    const uint4* gsrc = (const uint4*)(attn + rowbase * 256);
#pragma unroll
    for (int u = 0; u < 8; u++) {
      const int idx = u * 256 + t;
      const int row = idx >> 5, c8 = idx & 31;
      *(uint4*)&Ah[row * 264 + c8 * 8] = gsrc[idx];
    }
  }
  __syncthreads();

  // ---- GEMM0: out-proj (K=256), depth-2 weight prefetch, full unroll
  f32x4 acc0[4][4] = {};
  {
    const size_t wb = (size_t)(w * 64 + lr) * 256 + lq * 8;
    bf16x8 wf0[2][4];
#pragma unroll
    for (int d = 0; d < 2; d++)
#pragma unroll
      for (int j = 0; j < 4; j++)
        wf0[d][j] = *(const bf16x8*)&Wot[wb + (size_t)j * 4096 + d * 32];
#pragma unroll
    for (int ks = 0; ks < 8; ks++) {
      bf16x8 c0 = wf0[ks & 1][0], c1 = wf0[ks & 1][1];
      bf16x8 c2 = wf0[ks & 1][2], c3 = wf0[ks & 1][3];
      if (ks + 2 < 8) {
#pragma unroll
        for (int j = 0; j < 4; j++)
          wf0[ks & 1][j] = *(const bf16x8*)&Wot[wb + (size_t)j * 4096 + (ks + 2) * 32];
      }
      bf16x8 af[4];
#pragma unroll
      for (int i = 0; i < 4; i++)
        af[i] = *(const bf16x8*)&Ah[(i * 16 + lr) * 264 + ks * 32 + lq * 8];
#pragma unroll
      for (int i = 0; i < 4; i++) {
        acc0[i][0] = __builtin_amdgcn_mfma_f32_16x16x32_bf16(af[i], c0, acc0[i][0], 0, 0, 0);
        acc0[i][1] = __builtin_amdgcn_mfma_f32_16x16x32_bf16(af[i], c1, acc0[i][1], 0, 0, 0);
        acc0[i][2] = __builtin_amdgcn_mfma_f32_16x16x32_bf16(af[i], c2, acc0[i][2], 0, 0, 0);
        acc0[i][3] = __builtin_amdgcn_mfma_f32_16x16x32_bf16(af[i], c3, acc0[i][3], 0, 0, 0);
      }
    }
  }
  // ---- epilogue0: +b_out +res(src) ; LN1 ; h -> Ah (bf16, in place)
  {
    float vsum[4][4], vsq[4][4];
#pragma unroll
    for (int i = 0; i < 4; i++)
#pragma unroll
      for (int r = 0; r < 4; r++) { vsum[i][r] = 0.f; vsq[i][r] = 0.f; }
#pragma unroll
    for (int j = 0; j < 4; j++) {
      const int col = w * 64 + j * 16 + lr;
      const float bv = b_out[col];
#pragma unroll
      for (int i = 0; i < 4; i++)
#pragma unroll
        for (int r = 0; r < 4; r++) {
          const int row = i * 16 + lq * 4 + r;
          float v = acc0[i][j][r] + bv + bf2f(srcres[(rowbase + row) * 256 + col]);
          acc0[i][j][r] = v;
          vsum[i][r] += v;
          vsq[i][r]  += v * v;
        }
    }
#pragma unroll
    for (int m = 1; m <= 8; m <<= 1)
#pragma unroll
      for (int i = 0; i < 4; i++)
#pragma unroll
        for (int r = 0; r < 4; r++) {
          vsum[i][r] += __shfl_xor(vsum[i][r], m, 64);
          vsq[i][r]  += __shfl_xor(vsq[i][r],  m, 64);
        }
    if (lr == 0) {
#pragma unroll
      for (int i = 0; i < 4; i++)
#pragma unroll
        for (int r = 0; r < 4; r++) {
          const int row = i * 16 + lq * 4 + r;
          red[0][w][row] = vsum[i][r];
          red[1][w][row] = vsq[i][r];
        }
    }
    __syncthreads();
    float mu[4][4], rstd[4][4];
#pragma unroll
    for (int i = 0; i < 4; i++)
#pragma unroll
      for (int r = 0; r < 4; r++) {
        const int row = i * 16 + lq * 4 + r;
        const float ts = red[0][0][row] + red[0][1][row] + red[0][2][row] + red[0][3][row];
        const float tq = red[1][0][row] + red[1][1][row] + red[1][2][row] + red[1][3][row];
        const float m_ = ts * (1.f / 256.f);
        mu[i][r] = m_;
        rstd[i][r] = rsqrtf(tq * (1.f / 256.f) - m_ * m_ + 1e-5f);
      }
#pragma unroll
    for (int j = 0; j < 4; j++) {
      const int col = w * 64 + j * 16 + lr;
      const float gg = g1[col], bb = be1[col];
#pragma unroll
      for (int i = 0; i < 4; i++)
#pragma unroll
        for (int r = 0; r < 4; r++) {
          const int row = i * 16 + lq * 4 + r;
          const float y = (acc0[i][j][r] - mu[i][r]) * rstd[i][r] * gg + bb;
          Ah[row * 264 + col] = f2bf(y);
        }
    }
  }
  __syncthreads();

  // ---- FFN: 8 chunks of 128 hidden cols; deep weight prefetch
  f32x4 acc2[4][4] = {};
  const int c1base = w * 32;
#pragma unroll 1
  for (int c2 = 0; c2 < 8; c2++) {
    f32x4 acc1[4][2] = {};
    const size_t w1r0 = (size_t)(c2 * 128 + c1base + lr) * 256 + lq * 8;
    const size_t w1r1 = w1r0 + (size_t)16 * 256;
    bf16x8 wf[4][2];
#pragma unroll
    for (int d = 0; d < 4; d++) {
      wf[d][0] = *(const bf16x8*)&W1t[w1r0 + d * 32];
      wf[d][1] = *(const bf16x8*)&W1t[w1r1 + d * 32];
    }
#pragma unroll
    for (int ks = 0; ks < 8; ks++) {
      bf16x8 b0 = wf[ks & 3][0], b1v = wf[ks & 3][1];
      if (ks + 4 < 8) {
        wf[ks & 3][0] = *(const bf16x8*)&W1t[w1r0 + (ks + 4) * 32];
        wf[ks & 3][1] = *(const bf16x8*)&W1t[w1r1 + (ks + 4) * 32];
      }
      bf16x8 af[4];
#pragma unroll
      for (int i = 0; i < 4; i++)
        af[i] = *(const bf16x8*)&Ah[(i * 16 + lr) * 264 + ks * 32 + lq * 8];
#pragma unroll
      for (int i = 0; i < 4; i++) {
        acc1[i][0] = __builtin_amdgcn_mfma_f32_16x16x32_bf16(af[i], b0,  acc1[i][0], 0, 0, 0);
        acc1[i][1] = __builtin_amdgcn_mfma_f32_16x16x32_bf16(af[i], b1v, acc1[i][1], 0, 0, 0);
      }
    }
    __syncthreads();
#pragma unroll
    for (int j = 0; j < 2; j++) {
      const int colc = c1base + j * 16 + lr;
      const float bv = b1[c2 * 128 + colc];
#pragma unroll
      for (int i = 0; i < 4; i++)
#pragma unroll
        for (int r = 0; r < 4; r++)
          Hc[(i * 16 + lq * 4 + r) * 136 + colc] = f2bf(fmaxf(acc1[i][j][r] + bv, 0.f));
    }
    __syncthreads();
    const size_t w2b = (size_t)(w * 64 + lr) * 1024 + c2 * 128 + lq * 8;
    bf16x8 wg[2][4];
#pragma unroll
    for (int d = 0; d < 2; d++)
#pragma unroll
      for (int j = 0; j < 4; j++)
        wg[d][j] = *(const bf16x8*)&W2t[w2b + (size_t)j * 16384 + d * 32];
#pragma unroll
    for (int ks = 0; ks < 4; ks++) {
      bf16x8 c0 = wg[ks & 1][0], c1 = wg[ks & 1][1];
      bf16x8 cc2 = wg[ks & 1][2], c3 = wg[ks & 1][3];
      if (ks + 2 < 4) {
#pragma unroll
        for (int j = 0; j < 4; j++)
          wg[ks & 1][j] = *(const bf16x8*)&W2t[w2b + (size_t)j * 16384 + (ks + 2) * 32];
      }
      bf16x8 af2[4];
#pragma unroll
      for (int i = 0; i < 4; i++)
        af2[i] = *(const bf16x8*)&Hc[(i * 16 + lr) * 136 + ks * 32 + lq * 8];
#pragma unroll
      for (int i = 0; i < 4; i++) {
        acc2[i][0] = __builtin_amdgcn_mfma_f32_16x16x32_bf16(af2[i], c0,  acc2[i][0], 0, 0, 0);
        acc2[i][1] = __builtin_amdgcn_mfma_f32_16x16x32_bf16(af2[i], c1,  acc2[i][1], 0, 0, 0);
        acc2[i][2] = __builtin_amdgcn_mfma_f32_16x16x32_bf16(af2[i], cc2, acc2[i][2], 0, 0, 0);
        acc2[i][3] = __builtin_amdgcn_mfma_f32_16x16x32_bf16(af2[i], c3,  acc2[i][3], 0, 0, 0);
      }
    }
  }
  // ---- epilogue2: +b2 +res(h from Ah) ; LN2 ; f32 out
  float vsum[4][4], vsq[4][4];
#pragma unroll
  for (int i = 0; i < 4; i++)
#pragma unroll
    for (int r = 0; r < 4; r++) { vsum[i][r] = 0.f; vsq[i][r] = 0.f; }
#pragma unroll
  for (int j = 0; j < 4; j++) {
    const int col = w * 64 + j * 16 + lr;
    const float bv = b2[col];
#pragma unroll
    for (int i = 0; i < 4; i++)
#pragma unroll
      for (int r = 0; r < 4; r++) {
        const int row = i * 16 + lq * 4 + r;
        float v = acc2[i][j][r] + bv + bf2f(Ah[row * 264 + col]);
        acc2[i][j][r] = v;
        vsum[i][r] += v;
        vsq[i][r]  += v * v;
      }
  }
#pragma unroll
  for (int m = 1; m <= 8; m <<= 1)
#pragma unroll
    for (int i = 0; i < 4; i++)
#pragma unroll
      for (int r = 0; r < 4; r++) {
        vsum[i][r] += __shfl_xor(vsum[i][r], m, 64);
        vsq[i][r]  += __shfl_xor(vsq[i][r],  m, 64);
      }
  __syncthreads();
  if (lr == 0) {
#pragma unroll
    for (int i = 0; i < 4; i++)
#pragma unroll
      for (int r = 0; r < 4; r++) {
        const int row = i * 16 + lq * 4 + r;
        red[0][w][row] = vsum[i][r];
        red[1][w][row] = vsq[i][r];
      }
  }
  __syncthreads();
  float mu[4][4], rstd[4][4];
#pragma unroll
  for (int i = 0; i < 4; i++)
#pragma unroll
    for (int r = 0; r < 4; r++) {
      const int row = i * 16 + lq * 4 + r;
      const float ts = red[0][0][row] + red[0][1][row] + red[0][2][row] + red[0][3][row];
      const float tq = red[1][0][row] + red[1][1][row] + red[1][2][row] + red[1][3][row];
      const float m_ = ts * (1.f / 256.f);
      mu[i][r] = m_;
      rstd[i][r] = rsqrtf(tq * (1.f / 256.f) - m_ * m_ + 1e-5f);
    }
#pragma unroll
  for (int j = 0; j < 4; j++) {
    const int col = w * 64 + j * 16 + lr;
    const float gg = g2[col], bb = be2[col];
#pragma unroll
    for (int i = 0; i < 4; i++)
#pragma unroll
      for (int r = 0; r < 4; r++) {
        const int row = i * 16 + lq * 4 + r;
        out[(rowbase + row) * 256 + col] = (acc2[i][j][r] - mu[i][r]) * rstd[i][r] * gg + bb;
      }
  }
}

// ---- bf16x8 (uint4) fused unpack + PACKED FMA (v_pk_fma_f32) into f32x2 acc
__device__ __forceinline__ void fma8(uint4 v, float w, f32x2* a) {
  const unsigned uu[4] = {v.x, v.y, v.z, v.w};
  const f32x2 w2 = {w, w};
#pragma unroll
  for (int i = 0; i < 4; i++) {
    union { unsigned u; float f; } lo, hi;
    lo.u = uu[i] << 16;
    hi.u = uu[i] & 0xffff0000u;
    f32x2 val = {lo.f, hi.f};
    a[i] += w2 * val;
  }
}

// ---- deformable attention: two-phase, int4 byte-offset tables (R8 structure)
// + T5 setprio around the FMA clusters (independent barrier-free waves = the
// regime where setprio measured +4-7%; null only on lockstep GEMMs).
__global__ __launch_bounds__(256) void deform_kernel(const unsigned short* __restrict__ valb,
                                                     const unsigned short* __restrict__ oab,
                                                     const float* __restrict__ refp,
                                                     unsigned short* __restrict__ outb) {
  __shared__ float4 sW[8][8][17];
  __shared__ int4   sI[8][8][17];
  const int t = threadIdx.x;
  const int bid = blockIdx.x;
  const int nb = (bid & 7) * 680 + (bid >> 3);
  const int tok0 = nb * 8;

  {
    const int g = t >> 5, h = (t >> 2) & 7, l = t & 3;
    const int tok = tok0 + g;
    const unsigned short* lg = oab + (size_t)tok * 384 + 256 + h * 16;
    uint4 lv0 = ((const uint4*)lg)[0];
    uint4 lv1 = ((const uint4*)lg)[1];
    const unsigned lw[8] = {lv0.x, lv0.y, lv0.z, lv0.w, lv1.x, lv1.y, lv1.z, lv1.w};
    float w[16];
#pragma unroll
    for (int i = 0; i < 8; i++) {
      union { unsigned u; float f; } lo, hi;
      lo.u = lw[i] << 16; hi.u = lw[i] & 0xffff0000u;
      w[2 * i] = lo.f; w[2 * i + 1] = hi.f;
    }
    float mx = -1e30f;
#pragma unroll
    for (int i = 0; i < 16; i++) mx = fmaxf(mx, w[i]);
    float s = 0.f;
#pragma unroll
    for (int i = 0; i < 16; i++) { w[i] = __expf(w[i] - mx); s += w[i]; }
    const float inv = 1.f / s;
    uint4 ov = *(const uint4*)(oab + (size_t)tok * 384 + h * 32 + l * 8);
    const unsigned owv[4] = {ov.x, ov.y, ov.z, ov.w};
    float off[8];
#pragma unroll
    for (int i = 0; i < 4; i++) {
      union { unsigned u; float f; } lo, hi;
      lo.u = owv[i] << 16; hi.u = owv[i] & 0xffff0000u;
      off[2 * i] = lo.f; off[2 * i + 1] = hi.f;
    }
    const float* rp = refp + (size_t)tok * 8 + l * 2;
    const int S = 128 >> l;
    const float Sf = (float)S;
    const float rx = rp[0] * Sf - 0.5f;
    const float ry = rp[1] * Sf - 0.5f;
#pragma unroll
    for (int p = 0; p < 4; p++) {
      const int idx = l * 4 + p;
      const float x = rx + off[p * 2 + 0];
      const float y = ry + off[p * 2 + 1];
      const float aw = w[idx] * inv;
      const float x0f = floorf(x), y0f = floorf(y);
      const int x0 = (int)x0f, y0 = (int)y0f;
      const float fx = x - x0f, fy = y - y0f;
      const bool xin0 = (x0 >= 0) & (x0 < S), xin1 = (x0 + 1 >= 0) & (x0 + 1 < S);
      const bool yin0 = (y0 >= 0) & (y0 < S), yin1 = (y0 + 1 >= 0) & (y0 + 1 < S);
      const int xc0 = min(max(x0, 0), S - 1), xc1 = min(max(x0 + 1, 0), S - 1);
      const int yc0 = min(max(y0, 0), S - 1), yc1 = min(max(y0 + 1, 0), S - 1);
      sW[g][h][idx] = make_float4(aw * (1.f - fx) * (1.f - fy) * (float)(xin0 & yin0),
                                  aw * fx * (1.f - fy)         * (float)(xin1 & yin0),
                                  aw * (1.f - fx) * fy         * (float)(xin0 & yin1),
                                  aw * fx * fy                 * (float)(xin1 & yin1));
      sI[g][h][idx] = make_int4((yc0 * S + xc0) << 9, (yc0 * S + xc1) << 9,
                                (yc1 * S + xc0) << 9, (yc1 * S + xc1) << 9);
    }
  }
  __syncthreads();

  const int g = t >> 5, h = (t >> 2) & 7, dc = t & 3;
  const int tok = tok0 + g;
  const int b = tok / LQN;
  f32x2 acc[4] = {};
  const int ST[4] = {0, 16384, 20480, 21504};
#pragma unroll
  for (int l = 0; l < 4; l++) {
    const char* vbc = (const char*)(valb + ((size_t)(b * LQN + ST[l])) * 256 + h * 32 + dc * 8);
#pragma unroll
    for (int p = 0; p < 4; p++) {
      float4 W4 = sW[g][h][l * 4 + p];
      int4   I4 = sI[g][h][l * 4 + p];
      uint4 v00 = *(const uint4*)(vbc + I4.x);
      uint4 v10 = *(const uint4*)(vbc + I4.y);
      uint4 v01 = *(const uint4*)(vbc + I4.z);
      uint4 v11 = *(const uint4*)(vbc + I4.w);
      __builtin_amdgcn_s_setprio(1);
      fma8(v00, W4.x, acc);
      fma8(v10, W4.y, acc);
      fma8(v01, W4.z, acc);
      fma8(v11, W4.w, acc);
      __builtin_amdgcn_s_setprio(0);
    }
  }
  unsigned o[4];
#pragma unroll
  for (int i = 0; i < 4; i++)
    o[i] = (unsigned)f2bf(acc[i].x) | ((unsigned)f2bf(acc[i].y) << 16);
  *(uint4*)(outb + (size_t)tok * 256 + h * 32 + dc * 8) = make_uint4(o[0], o[1], o[2], o[3]);
}

extern "C" void kernel_launch(void* const* d_in, const int* in_sizes, int n_in,
                              void* d_out, int out_size, void* d_ws, size_t ws_size,
                              hipStream_t stream) {
  (void)in_sizes; (void)n_in; (void)out_size; (void)ws_size;
  const float* src    = (const float*)d_in[0];
  const float* pos    = (const float*)d_in[1];
  const float* refp   = (const float*)d_in[2];
  const float* W_off  = (const float*)d_in[3];
  const float* b_off  = (const float*)d_in[4];
  const float* W_attn = (const float*)d_in[5];
  const float* b_attn = (const float*)d_in[6];
  const float* W_val  = (const float*)d_in[7];
  const float* b_val  = (const float*)d_in[8];
  const float* W_out  = (const float*)d_in[9];
  const float* b_out  = (const float*)d_in[10];
  const float* ln1_g  = (const float*)d_in[11];
  const float* ln1_b  = (const float*)d_in[12];
  const float* W1     = (const float*)d_in[13];
  const float* b1     = (const float*)d_in[14];
  const float* W2     = (const float*)d_in[15];
  const float* b2     = (const float*)d_in[16];
  const float* ln2_g  = (const float*)d_in[17];
  const float* ln2_b  = (const float*)d_in[18];

  char* ws = (char*)d_ws;
  unsigned short* Wt_val = (unsigned short*)ws;          // 65536
  unsigned short* Wt_oa  = Wt_val + 65536;               // 98304
  unsigned short* Wt_out = Wt_oa + 98304;                // 65536
  unsigned short* Wt_1   = Wt_out + 65536;               // 262144
  unsigned short* Wt_2   = Wt_1 + 262144;                // 262144
  float*          b_oa   = (float*)(Wt_2 + 262144);      // 384
  const size_t WPOOL = 2u * 1024 * 1024;

  const size_t SZ_bf = (size_t)TOKS * 256 * 2;           // 22.3 MB
  const size_t SZ_oa = (size_t)TOKS * 384 * 2;           // 33.4 MB

  unsigned short* srcb = (unsigned short*)(ws + WPOOL);
  unsigned short* qb   = (unsigned short*)(ws + WPOOL + SZ_bf);
  unsigned short* valb = (unsigned short*)(ws + WPOOL + 2 * SZ_bf);
  unsigned short* oab  = (unsigned short*)(ws + WPOOL + 3 * SZ_bf);
  // alias (lifetime-disjoint):
  unsigned short* attnoutb = qb;     // deform out; qb dead after proj

  // 1. prep + LDS-tiled weight transposes + bias concat
  prewt_kernel<<<11617, 256, 0, stream>>>(src, pos, srcb, qb,
                                          W_val, W_off, W_attn, W_out, W1, W2, b_off, b_attn,
                                          Wt_val, Wt_oa, Wt_out, Wt_1, Wt_2, b_oa);

  // 2. merged projections: value (N=256) + off/attn (N=384)
  proj_kernel<<<dim3(340, 5), 256, 0, stream>>>(srcb, qb, Wt_val, Wt_oa, b_val, b_oa,
                                                valb, oab);

  // 3. deformable attention (8 tokens/block, XCD-swizzled)
  deform_kernel<<<TOKS / 8, 256, 0, stream>>>(valb, oab, refp, attnoutb);

  // 4. fused tail: out-proj + res(src) + LN1 + FFN + res(h) + LN2 -> d_out (f32)
  fused_tail_kernel<<<680, 256, 0, stream>>>(attnoutb, Wt_out, b_out, srcb, ln1_g, ln1_b,
                                             Wt_1, Wt_2, b1, b2, ln2_g, ln2_b,
                                             (float*)d_out);
}